// Round 17
// baseline (3648.103 us; speedup 1.0000x reference)
//
#include <hip/hip_runtime.h>
#include <hip/hip_bf16.h>

#define Bsz 4096
#define Dsz 256
#define Hsz 512
#define Tsz 45

typedef __attribute__((ext_vector_type(8))) short short8;
typedef __attribute__((ext_vector_type(4))) float f32x4;
typedef __attribute__((ext_vector_type(4))) unsigned short us4;
typedef __attribute__((ext_vector_type(2))) long lx2;
using bf16 = __hip_bfloat16;
using u8 = unsigned char;

__device__ __forceinline__ float sigf(float x)   { return 1.0f / (1.0f + __expf(-x)); }
__device__ __forceinline__ float tanhft(float x) { return 1.0f - 2.0f / (__expf(2.0f * x) + 1.0f); }
__device__ __forceinline__ float b2f(unsigned short u) { return __uint_as_float((unsigned)u << 16); }
__device__ __forceinline__ u8 f2fp8(float v) {
    int p = __builtin_amdgcn_cvt_pk_fp8_f32(v, v, 0, false);
    return (u8)(p & 0xff);
}

#define WAIT_VM(N) asm volatile("s_waitcnt vmcnt(" #N ")" ::: "memory")

// ---------------------------------------------------------------------------
// Weight convert/pack (one-shot, identical to R16 — proven numerics).
// PAIR-PACKED fragment blocks: per (kt,wave) the 16 frags live as 8 x 1 KB
// pair-blocks; pair p holds frag 2p in lane bytes [0:8) and 2p+1 in [8:16).
// ---------------------------------------------------------------------------
__global__ void k_conv(const float* __restrict__ ef,   const float* __restrict__ ctx,
                       const float* __restrict__ Whi,  const float* __restrict__ Wci,
                       const float* __restrict__ Wih0, const float* __restrict__ Whh0,
                       const float* __restrict__ Wih1, const float* __restrict__ Whh1,
                       const float* __restrict__ Wo1,  const float* __restrict__ Wg1,
                       bf16* __restrict__ efb,  bf16* __restrict__ ctxb,
                       bf16* __restrict__ Wit,  u8* __restrict__ W0p,
                       u8* __restrict__ W1p,  u8* __restrict__ Wo1p,
                       u8* __restrict__ Wg1p)
{
    size_t tid = (size_t)blockIdx.x * blockDim.x + threadIdx.x;
    size_t gsz = (size_t)gridDim.x * blockDim.x;
    for (size_t i = tid; i < (size_t)Bsz * Dsz; i += gsz) {
        efb[i]  = __float2bfloat16(ef[i]);
        ctxb[i] = __float2bfloat16(ctx[i]);
    }
    for (size_t i = tid; i < 2048ull * 512 / 4; i += gsz) {   // W0p <- Whh0^T
        int n = i >> 7, k = (i & 127) * 4;
        int lo = __builtin_amdgcn_cvt_pk_fp8_f32(Whh0[(size_t)(k+0)*2048+n], Whh0[(size_t)(k+1)*2048+n], 0, false);
        int pk = __builtin_amdgcn_cvt_pk_fp8_f32(Whh0[(size_t)(k+2)*2048+n], Whh0[(size_t)(k+3)*2048+n], lo, true);
        int nb = n >> 4;
        int q = ((nb >> 5) << 2) + (nb & 3);
        size_t dst = (((size_t)(k >> 5) * 8 + ((nb >> 2) & 7)) * 8 + (q >> 1)) * 1024
                   + ((k >> 3) & 3) * 256 + (n & 15) * 16 + (q & 1) * 8 + (k & 4);
        *(int*)(W0p + dst) = pk;
    }
    for (size_t i = tid; i < 2048ull * 1024 / 4; i += gsz) {  // W1p <- [Wih1;Whh1]^T
        int n = i >> 8, k = (i & 255) * 4;
        float f0, f1, f2, f3;
        if (k < 512) {
            f0 = Wih1[(size_t)(k+0)*2048+n]; f1 = Wih1[(size_t)(k+1)*2048+n];
            f2 = Wih1[(size_t)(k+2)*2048+n]; f3 = Wih1[(size_t)(k+3)*2048+n];
        } else {
            int kk = k - 512;
            f0 = Whh1[(size_t)(kk+0)*2048+n]; f1 = Whh1[(size_t)(kk+1)*2048+n];
            f2 = Whh1[(size_t)(kk+2)*2048+n]; f3 = Whh1[(size_t)(kk+3)*2048+n];
        }
        int lo = __builtin_amdgcn_cvt_pk_fp8_f32(f0, f1, 0, false);
        int pk = __builtin_amdgcn_cvt_pk_fp8_f32(f2, f3, lo, true);
        int nb = n >> 4;
        int q = ((nb >> 5) << 2) + (nb & 3);
        size_t dst = (((size_t)(k >> 5) * 8 + ((nb >> 2) & 7)) * 8 + (q >> 1)) * 1024
                   + ((k >> 3) & 3) * 256 + (n & 15) * 16 + (q & 1) * 8 + (k & 4);
        *(int*)(W1p + dst) = pk;
    }
    for (size_t i = tid; i < 32ull * 512 / 4; i += gsz) {     // Wo1p/Wg1p (N=32, nb*16+kt, b64 layout)
        int n = i >> 7, k = (i & 127) * 4;
        size_t dst = ((size_t)(n >> 4) * 16 + (k >> 5)) * 512 + ((k >> 3) & 3) * 128 + (n & 15) * 8 + (k & 4);
        int lo = __builtin_amdgcn_cvt_pk_fp8_f32(Wo1[(size_t)(k+0)*32+n], Wo1[(size_t)(k+1)*32+n], 0, false);
        int pk = __builtin_amdgcn_cvt_pk_fp8_f32(Wo1[(size_t)(k+2)*32+n], Wo1[(size_t)(k+3)*32+n], lo, true);
        *(int*)(Wo1p + dst) = pk;
        lo = __builtin_amdgcn_cvt_pk_fp8_f32(Wg1[(size_t)(k+0)*32+n], Wg1[(size_t)(k+1)*32+n], 0, false);
        pk = __builtin_amdgcn_cvt_pk_fp8_f32(Wg1[(size_t)(k+2)*32+n], Wg1[(size_t)(k+3)*32+n], lo, true);
        *(int*)(Wg1p + dst) = pk;
    }
    for (size_t i = tid; i < 4096ull * 256; i += gsz) {       // Wit[n][k] bf16
        size_t n = i >> 8, k = i & 255;
        float v = (n < 1024) ? Whi[k * 1024 + n]
                : (n < 2048) ? Wci[k * 1024 + (n - 1024)]
                             : Wih0[(1 + k) * 2048 + (n - 2048)];
        Wit[i] = __float2bfloat16(v);
    }
}

// ---------------------------------------------------------------------------
// Init GEMM (bf16): h stored fp8 plain [b][512], c f32, ctxg bf16 [b][j][4g].
// ---------------------------------------------------------------------------
__global__ void __launch_bounds__(256)
k_init(const bf16* __restrict__ efb, const bf16* __restrict__ ctxb,
       const bf16* __restrict__ Wit,
       const float* __restrict__ bh,  const float* __restrict__ bc,
       const float* __restrict__ bi0, const float* __restrict__ bh0,
       u8* __restrict__ h0, u8* __restrict__ h1,
       float* __restrict__ c0, float* __restrict__ c1,
       bf16* __restrict__ ctxg)
{
    const int t = threadIdx.x, lane = t & 63, w = t >> 6;
    const int wr = w >> 1, wc = w & 1;
    const int lq = lane >> 4, ln = lane & 15;
    const int m0 = blockIdx.x * 128, n0 = blockIdx.y * 64;
    const bf16* A = (n0 < 2048) ? efb : ctxb;

    f32x4 zero = {0.f, 0.f, 0.f, 0.f};
    f32x4 acc[4][2];
#pragma unroll
    for (int r = 0; r < 4; ++r)
#pragma unroll
        for (int c = 0; c < 2; ++c) acc[r][c] = zero;

    for (int k0 = 0; k0 < 256; k0 += 32) {
        short8 af[4];
#pragma unroll
        for (int r = 0; r < 4; ++r)
            af[r] = *(const short8*)(A + (size_t)(m0 + wr * 64 + r * 16 + ln) * 256 + k0 + lq * 8);
#pragma unroll
        for (int c = 0; c < 2; ++c) {
            short8 bv = *(const short8*)(Wit + (size_t)(n0 + wc * 32 + c * 16 + ln) * 256 + k0 + lq * 8);
#pragma unroll
            for (int r = 0; r < 4; ++r)
                acc[r][c] = __builtin_amdgcn_mfma_f32_16x16x32_bf16(af[r], bv, acc[r][c], 0, 0, 0);
        }
    }
#pragma unroll
    for (int r = 0; r < 4; ++r)
#pragma unroll
        for (int c = 0; c < 2; ++c)
#pragma unroll
            for (int e = 0; e < 4; ++e) {
                int b = m0 + wr * 64 + r * 16 + lq * 4 + e;
                int n = n0 + wc * 32 + c * 16 + ln;
                float v = acc[r][c][e];
                if (n < 1024) {
                    v += bh[n];
                    if (n < 512) h0[(size_t)b * 512 + n]       = f2fp8(v);
                    else         h1[(size_t)b * 512 + n - 512] = f2fp8(v);
                } else if (n < 2048) {
                    int m = n - 1024; v += bc[m];
                    if (m < 512) c0[(size_t)b * 512 + m]       = v;
                    else         c1[(size_t)b * 512 + m - 512] = v;
                } else {
                    int j = n - 2048;
                    ctxg[(size_t)b * 2048 + (j & 511) * 4 + (j >> 9)] =
                        __float2bfloat16(v + bi0[j] + bh0[j]);
                }
            }
}

// h-LDS B-frag read (B[k][b=ln]): row=ln, chunk c=4kt+lq, swizzle c^ln (4-bit)
__device__ __forceinline__ long hread(const u8* buf, int ln, int lq, int kt) {
    int c = (kt << 2) + lq;
    return *(const long*)(buf + ln * 512 + ((c ^ ln) << 3));
}

// load one 4 KB half-kt of the wave's weight stream DIRECTLY into registers:
// 4 x global_load_dwordx4 (16 B/lane, coalesced) -> buf[0..3]
__device__ __forceinline__ void loadH(const u8* __restrict__ Wp, int w, int h,
                                      lx2 (&buf)[4], int lane) {
    const u8* src = Wp + ((size_t)((h >> 1) * 8 + w) << 13) + ((size_t)(h & 1) << 12) + lane * 16;
#pragma unroll
    for (int i = 0; i < 4; ++i)
        buf[i] = *(const lx2*)(src + i * 1024);
}

// 8 MFMA of one half-kt from a register slot (pair-packed frags)
template <int QB>
__device__ __forceinline__ void mfma8(const lx2 (&buf)[4], long bf, f32x4 (&acc)[4][4]) {
#pragma unroll
    for (int i = 0; i < 4; ++i) {
        acc[(QB + 2 * i) & 3][(QB + 2 * i) >> 2] =
            __builtin_amdgcn_mfma_f32_16x16x32_fp8_fp8(buf[i][0], bf, acc[(QB + 2 * i) & 3][(QB + 2 * i) >> 2], 0, 0, 0);
        acc[(QB + 2 * i + 1) & 3][(QB + 2 * i + 1) >> 2] =
            __builtin_amdgcn_mfma_f32_16x16x32_fp8_fp8(buf[i][1], bf, acc[(QB + 2 * i + 1) & 3][(QB + 2 * i + 1) >> 2], 0, 0, 0);
    }
}

// ---------------------------------------------------------------------------
// Persistent T-loop kernel. 256 WGs x 512 thr (16 rows x all 2048 cols/WG).
// Weights stream global->VGPR through a ring-4 of register half-slots
// (wf0..wf3, 64 VGPRs), counted vmcnt(8), seamless across layer/step
// boundaries. NO LDS traffic for weights (R16's ~25 us/step LDS round-trip
// eliminated). launch_bounds(512,1) -> 256-VGPR budget (R12's spill fixed).
// ---------------------------------------------------------------------------
__global__ void __launch_bounds__(512, 1)
k_loop(const u8* __restrict__ h0i, const u8* __restrict__ h1i,
       const u8* __restrict__ W0p, const u8* __restrict__ W1p,
       const u8* __restrict__ Wo1p, const u8* __restrict__ Wg1p,
       const bf16* __restrict__ ctxg, const float* __restrict__ ii,
       const float* __restrict__ w0row,
       const float* __restrict__ bi1, const float* __restrict__ bh1,
       const float* __restrict__ bo1, const float* __restrict__ Wo2,
       const float* __restrict__ bo2,
       const float* __restrict__ bg1, const float* __restrict__ Wg2,
       const float* __restrict__ bg2,
       const float* __restrict__ c0g, const float* __restrict__ c1g,
       float* __restrict__ out)
{
    __shared__ u8 h0L[8192];
    __shared__ u8 h1L[8192];
    __shared__ unsigned short a0Lb[2048];    // w0row as bf16
    __shared__ unsigned short a1Lb[2048];    // bi1+bh1 as bf16
    __shared__ float sit[16];
    __shared__ float spart[16][2];

    const int t = threadIdx.x, lane = t & 63, w = t >> 6;
    const int ln = lane & 15, lq = lane >> 4;
    const int m0 = blockIdx.x * 16;
    const int b = m0 + ln;
    f32x4 zero = {0.f, 0.f, 0.f, 0.f};

    // ---- prologue: h-init -> LDS (swizzled chunk^row); biases -> LDS bf16
#pragma unroll
    for (int i = 0; i < 2; ++i) {
        int cid = i * 512 + t;
        int row = cid >> 6, c = cid & 63;
        long v0 = *(const long*)(h0i + (size_t)(m0 + row) * 512 + c * 8);
        long v1 = *(const long*)(h1i + (size_t)(m0 + row) * 512 + c * 8);
        int pc = row * 512 + ((c ^ row) << 3);
        *(long*)(&h0L[pc]) = v0;
        *(long*)(&h1L[pc]) = v1;
    }
#pragma unroll
    for (int i = 0; i < 4; ++i) {
        int idx = i * 512 + t;
        a0Lb[idx] = (unsigned short)(__bfloat16_as_ushort(__float2bfloat16(w0row[idx])));
        a1Lb[idx] = (unsigned short)(__bfloat16_as_ushort(__float2bfloat16(bi1[idx] + bh1[idx])));
    }
    // ---- per-thread resident state: c and ctxg at (b=ln, jl=(w*4+jc)*16+lq*4+e)
    f32x4 cr0[4], cr1[4];
    us4 xg[4][4];
#pragma unroll
    for (int jc = 0; jc < 4; ++jc) {
        int jlb = (w * 4 + jc) * 16 + lq * 4;
        cr0[jc] = *(const f32x4*)(c0g + (size_t)b * 512 + jlb);
        cr1[jc] = *(const f32x4*)(c1g + (size_t)b * 512 + jlb);
#pragma unroll
        for (int e = 0; e < 4; ++e)
            xg[jc][e] = *(const us4*)((const unsigned short*)ctxg + (size_t)b * 2048 + (jlb + e) * 4);
    }
    __syncthreads();

    // intent head: waves 0,1 do j-tiles 0,1; all threads call (barriers inside)
    auto head2 = [&](const u8* Wp, const float* b1, const float* W2, float b2s,
                     bool tosit, float* dst, int stride, int scol) {
        if (w < 2) {
            f32x4 acc = zero;
#pragma unroll
            for (int kt = 0; kt < 16; ++kt) {
                long bf = hread(h1L, ln, lq, kt);
                long af = *(const long*)(Wp + (size_t)(w * 16 + kt) * 512 + lane * 8);
                acc = __builtin_amdgcn_mfma_f32_16x16x32_fp8_fp8(af, bf, acc, 0, 0, 0);
            }
            float v = 0.f;
#pragma unroll
            for (int e = 0; e < 4; ++e) {
                int j = w * 16 + lq * 4 + e;
                v += fmaxf(acc[e] + b1[j], 0.f) * W2[j];
            }
            v += __shfl_xor(v, 16);
            v += __shfl_xor(v, 32);
            if (lq == 0) spart[ln][w] = v;
        }
        __syncthreads();
        if (t < 16) {
            float pv = sigf(spart[t][0] + spart[t][1] + b2s);
            if (tosit) sit[t] = pv;
            if (dst) dst[(size_t)(m0 + t) * stride + scol] = pv;
        }
        __syncthreads();
    };

    // register ring (4 half-slots x 4 lx2 = 64 VGPRs), persists across layers
    lx2 wf0[4], wf1[4], wf2[4], wf3[4];

    // seed the ring for step 0's layer 0 (12 loads in flight)
    loadH(W0p, w, 0, wf0, lane);
    loadH(W0p, w, 1, wf1, lane);
    loadH(W0p, w, 2, wf2, lane);

    for (int s = 0; s < Tsz; ++s) {
        if (s == 0) {
            if (t < 16) sit[t] = ii[m0 + t];
            __syncthreads();
        } else {
            head2(Wo1p, bo1, Wo2, bo2[0], true, out, Tsz, s - 1);
        }
        const float sval = sit[ln];

        // ================= layer 0: G = W0·h0^T, K=512 (32 halves) =========
        {
            f32x4 acc[4][4];
#pragma unroll
            for (int jc = 0; jc < 4; ++jc)
#pragma unroll
                for (int g = 0; g < 4; ++g) acc[jc][g] = zero;

            for (int k2 = 0; k2 < 7; ++k2) {          // halves 0..27
                long bfa = hread(h0L, ln, lq, 2 * k2);
                WAIT_VM(8); mfma8<0>(wf0, bfa, acc); loadH(W0p, w, 4 * k2 + 3, wf3, lane);
                WAIT_VM(8); mfma8<8>(wf1, bfa, acc); loadH(W0p, w, 4 * k2 + 4, wf0, lane);
                long bfb = hread(h0L, ln, lq, 2 * k2 + 1);
                WAIT_VM(8); mfma8<0>(wf2, bfb, acc); loadH(W0p, w, 4 * k2 + 5, wf1, lane);
                WAIT_VM(8); mfma8<8>(wf3, bfb, acc); loadH(W0p, w, 4 * k2 + 6, wf2, lane);
            }
            {   // halves 28..31; tail loads pre-stage layer-1's halves 0..2
                long bfa = hread(h0L, ln, lq, 14);
                WAIT_VM(8); mfma8<0>(wf0, bfa, acc); loadH(W0p, w, 31, wf3, lane);
                WAIT_VM(8); mfma8<8>(wf1, bfa, acc); loadH(W1p, w, 0, wf0, lane);
                long bfb = hread(h0L, ln, lq, 15);
                WAIT_VM(8); mfma8<0>(wf2, bfb, acc); loadH(W1p, w, 1, wf1, lane);
                WAIT_VM(8); mfma8<8>(wf3, bfb, acc); loadH(W1p, w, 2, wf2, lane);
            }
            // epilogue: cell from resident state only; L1 loads fly meanwhile
            int hold[4];
#pragma unroll
            for (int jc = 0; jc < 4; ++jc) {
                int jlb = (w * 4 + jc) * 16 + lq * 4;
                us4 a0v[4];
#pragma unroll
                for (int g = 0; g < 4; ++g) a0v[g] = *(const us4*)(a0Lb + g * 512 + jlb);
                float hv[4];
#pragma unroll
                for (int e = 0; e < 4; ++e) {
                    float pre[4];
#pragma unroll
                    for (int g = 0; g < 4; ++g)
                        pre[g] = acc[jc][g][e] + b2f(xg[jc][e][g]) + sval * b2f(a0v[g][e]);
                    float ig = sigf(pre[0]), fg = sigf(pre[1]);
                    float gg = tanhft(pre[2]), og = sigf(pre[3]);
                    float cn = fg * cr0[jc][e] + ig * gg;
                    cr0[jc][e] = cn;
                    hv[e] = og * tanhft(cn);
                }
                int lo = __builtin_amdgcn_cvt_pk_fp8_f32(hv[0], hv[1], 0, false);
                hold[jc] = __builtin_amdgcn_cvt_pk_fp8_f32(hv[2], hv[3], lo, true);
            }
            __syncthreads();                          // all done reading h0L
#pragma unroll
            for (int jc = 0; jc < 4; ++jc) {
                int c = (w * 4 + jc) * 2 + (lq >> 1);
                *(int*)(h0L + ln * 512 + ((c ^ ln) << 3) + (lq & 1) * 4) = hold[jc];
            }
            asm volatile("s_waitcnt lgkmcnt(0)" ::: "memory");
            __syncthreads();                          // h0 new visible
        }

        // ====== layer 1: G = W1·[h0;h1]^T, K=1024 (64 halves) ==============
        {
            f32x4 acc[4][4];
#pragma unroll
            for (int jc = 0; jc < 4; ++jc)
#pragma unroll
                for (int g = 0; g < 4; ++g) acc[jc][g] = zero;

            for (int k2 = 0; k2 < 8; ++k2) {          // halves 0..31 (bf from h0L)
                long bfa = hread(h0L, ln, lq, 2 * k2);
                WAIT_VM(8); mfma8<0>(wf0, bfa, acc); loadH(W1p, w, 4 * k2 + 3, wf3, lane);
                WAIT_VM(8); mfma8<8>(wf1, bfa, acc); loadH(W1p, w, 4 * k2 + 4, wf0, lane);
                long bfb = hread(h0L, ln, lq, 2 * k2 + 1);
                WAIT_VM(8); mfma8<0>(wf2, bfb, acc); loadH(W1p, w, 4 * k2 + 5, wf1, lane);
                WAIT_VM(8); mfma8<8>(wf3, bfb, acc); loadH(W1p, w, 4 * k2 + 6, wf2, lane);
            }
            for (int k2 = 8; k2 < 15; ++k2) {         // halves 32..59 (bf from h1L)
                long bfa = hread(h1L, ln, lq, 2 * k2 - 16);
                WAIT_VM(8); mfma8<0>(wf0, bfa, acc); loadH(W1p, w, 4 * k2 + 3, wf3, lane);
                WAIT_VM(8); mfma8<8>(wf1, bfa, acc); loadH(W1p, w, 4 * k2 + 4, wf0, lane);
                long bfb = hread(h1L, ln, lq, 2 * k2 - 15);
                WAIT_VM(8); mfma8<0>(wf2, bfb, acc); loadH(W1p, w, 4 * k2 + 5, wf1, lane);
                WAIT_VM(8); mfma8<8>(wf3, bfb, acc); loadH(W1p, w, 4 * k2 + 6, wf2, lane);
            }
            {   // halves 60..63; tail loads pre-stage next step's L0 halves 0..2
                long bfa = hread(h1L, ln, lq, 14);
                WAIT_VM(8); mfma8<0>(wf0, bfa, acc); loadH(W1p, w, 63, wf3, lane);
                WAIT_VM(8); mfma8<8>(wf1, bfa, acc); loadH(W0p, w, 0, wf0, lane);
                long bfb = hread(h1L, ln, lq, 15);
                WAIT_VM(8); mfma8<0>(wf2, bfb, acc); loadH(W0p, w, 1, wf1, lane);
                WAIT_VM(8); mfma8<8>(wf3, bfb, acc); loadH(W0p, w, 2, wf2, lane);
            }
            int hold[4];
#pragma unroll
            for (int jc = 0; jc < 4; ++jc) {
                int jlb = (w * 4 + jc) * 16 + lq * 4;
                us4 a1v[4];
#pragma unroll
                for (int g = 0; g < 4; ++g) a1v[g] = *(const us4*)(a1Lb + g * 512 + jlb);
                float hv[4];
#pragma unroll
                for (int e = 0; e < 4; ++e) {
                    float pre[4];
#pragma unroll
                    for (int g = 0; g < 4; ++g) pre[g] = acc[jc][g][e] + b2f(a1v[g][e]);
                    float ig = sigf(pre[0]), fg = sigf(pre[1]);
                    float gg = tanhft(pre[2]), og = sigf(pre[3]);
                    float cn = fg * cr1[jc][e] + ig * gg;
                    cr1[jc][e] = cn;
                    hv[e] = og * tanhft(cn);
                }
                int lo = __builtin_amdgcn_cvt_pk_fp8_f32(hv[0], hv[1], 0, false);
                hold[jc] = __builtin_amdgcn_cvt_pk_fp8_f32(hv[2], hv[3], lo, true);
            }
            __syncthreads();                          // all done reading h1L
#pragma unroll
            for (int jc = 0; jc < 4; ++jc) {
                int c = (w * 4 + jc) * 2 + (lq >> 1);
                *(int*)(h1L + ln * 512 + ((c ^ ln) << 3) + (lq & 1) * 4) = hold[jc];
            }
            asm volatile("s_waitcnt lgkmcnt(0)" ::: "memory");
            __syncthreads();                          // h1 new visible
        }
    }

    // ---- final heads on the final h1 (in h1L); stray in-flight loads benign
    head2(Wo1p, bo1, Wo2, bo2[0], false, out, Tsz, 44);
    head2(Wg1p, bg1, Wg2, bg2[0], false, out + (size_t)Bsz * Tsz, 1, 0);
}

// ---------------------------------------------------------------------------
extern "C" void kernel_launch(void* const* d_in, const int* in_sizes, int n_in,
                              void* d_out, int out_size, void* d_ws, size_t ws_size,
                              hipStream_t stream)
{
    const float* ef   = (const float*)d_in[0];
    const float* ctx  = (const float*)d_in[1];
    const float* ii   = (const float*)d_in[2];
    const float* Whi  = (const float*)d_in[3];
    const float* bh   = (const float*)d_in[4];
    const float* Wci  = (const float*)d_in[5];
    const float* bc   = (const float*)d_in[6];
    const float* Wih0 = (const float*)d_in[7];
    const float* Whh0 = (const float*)d_in[8];
    const float* bi0  = (const float*)d_in[9];
    const float* bh0  = (const float*)d_in[10];
    const float* Wih1 = (const float*)d_in[11];
    const float* Whh1 = (const float*)d_in[12];
    const float* bi1  = (const float*)d_in[13];
    const float* bh1  = (const float*)d_in[14];
    const float* Wo1  = (const float*)d_in[15];
    const float* bo1  = (const float*)d_in[16];
    const float* Wo2  = (const float*)d_in[17];
    const float* bo2  = (const float*)d_in[18];
    const float* Wg1  = (const float*)d_in[19];
    const float* bg1  = (const float*)d_in[20];
    const float* Wg2  = (const float*)d_in[21];
    const float* bg2  = (const float*)d_in[22];
    float* out = (float*)d_out;

    char* ws = (char*)d_ws;
    size_t off = 0;
    auto take = [&](size_t bytes) -> char* {
        char* pp = ws + off;
        off += (bytes + 255) & ~(size_t)255;
        return pp;
    };
    u8*  W0p     = (u8*)take(2048ull * 512);
    u8*  W1p     = (u8*)take(2048ull * 1024);
    u8*  Wo1p    = (u8*)take(32ull * 512);
    u8*  Wg1p    = (u8*)take(32ull * 512);
    bf16* Wit    = (bf16*)take(4096ull * 256 * 2);
    bf16* efb    = (bf16*)take((size_t)Bsz * Dsz * 2);
    bf16* ctxb   = (bf16*)take((size_t)Bsz * Dsz * 2);
    u8*  h0x     = (u8*)take((size_t)Bsz * Hsz);
    u8*  h1x     = (u8*)take((size_t)Bsz * Hsz);
    float* c0    = (float*)take((size_t)Bsz * Hsz * 4);
    float* c1    = (float*)take((size_t)Bsz * Hsz * 4);
    bf16* ctxg   = (bf16*)take((size_t)Bsz * 2048 * 2);
    (void)ws_size; (void)in_sizes; (void)n_in; (void)out_size;

    k_conv<<<2048, 256, 0, stream>>>(ef, ctx, Whi, Wci, Wih0, Whh0, Wih1, Whh1, Wo1, Wg1,
                                     efb, ctxb, Wit, W0p, W1p, Wo1p, Wg1p);
    k_init<<<dim3(32, 64), 256, 0, stream>>>(efb, ctxb, Wit, bh, bc, bi0, bh0,
                                             h0x, h1x, c0, c1, ctxg);
    k_loop<<<256, 512, 0, stream>>>(h0x, h1x, W0p, W1p, Wo1p, Wg1p,
                                    ctxg, ii, Wih0, bi1, bh1,
                                    bo1, Wo2, bo2, bg1, Wg2, bg2,
                                    c0, c1, out);
}

// Round 18
// 3211.868 us; speedup vs baseline: 1.1358x; 1.1358x over previous
//
#include <hip/hip_runtime.h>
#include <hip/hip_bf16.h>

#define Bsz 4096
#define Dsz 256
#define Hsz 512
#define Tsz 45

typedef __attribute__((ext_vector_type(8))) short short8;
typedef __attribute__((ext_vector_type(4))) float f32x4;
typedef __attribute__((ext_vector_type(4))) unsigned short us4;
typedef __attribute__((ext_vector_type(2))) long lx2;
using bf16 = __hip_bfloat16;
using u8 = unsigned char;

__device__ __forceinline__ float sigf(float x)   { return 1.0f / (1.0f + __expf(-x)); }
__device__ __forceinline__ float tanhft(float x) { return 1.0f - 2.0f / (__expf(2.0f * x) + 1.0f); }
__device__ __forceinline__ float b2f(unsigned short u) { return __uint_as_float((unsigned)u << 16); }
__device__ __forceinline__ u8 f2fp8(float v) {
    int p = __builtin_amdgcn_cvt_pk_fp8_f32(v, v, 0, false);
    return (u8)(p & 0xff);
}

__device__ __forceinline__ void gload16(const void* g, void* l) {
    __builtin_amdgcn_global_load_lds((const __attribute__((address_space(1))) void*)g,
                                     (__attribute__((address_space(3))) void*)l, 16, 0, 0);
}

#define WAIT_VM(N) asm volatile("s_waitcnt vmcnt(" #N ")" ::: "memory")

// ---------------------------------------------------------------------------
// Weight convert/pack (one-shot, byte-identical to R16 — proven numerics).
// PAIR-PACKED fragment blocks: per (kt,wave) the 16 frags live as 8 x 1 KB
// pair-blocks; pair p holds frag 2p in lane bytes [0:8) and 2p+1 in [8:16).
// Quarter qt (2 KB) = pairs {2qt, 2qt+1} = frags 4qt..4qt+3, contiguous.
// ---------------------------------------------------------------------------
__global__ void k_conv(const float* __restrict__ ef,   const float* __restrict__ ctx,
                       const float* __restrict__ Whi,  const float* __restrict__ Wci,
                       const float* __restrict__ Wih0, const float* __restrict__ Whh0,
                       const float* __restrict__ Wih1, const float* __restrict__ Whh1,
                       const float* __restrict__ Wo1,  const float* __restrict__ Wg1,
                       bf16* __restrict__ efb,  bf16* __restrict__ ctxb,
                       bf16* __restrict__ Wit,  u8* __restrict__ W0p,
                       u8* __restrict__ W1p,  u8* __restrict__ Wo1p,
                       u8* __restrict__ Wg1p)
{
    size_t tid = (size_t)blockIdx.x * blockDim.x + threadIdx.x;
    size_t gsz = (size_t)gridDim.x * blockDim.x;
    for (size_t i = tid; i < (size_t)Bsz * Dsz; i += gsz) {
        efb[i]  = __float2bfloat16(ef[i]);
        ctxb[i] = __float2bfloat16(ctx[i]);
    }
    for (size_t i = tid; i < 2048ull * 512 / 4; i += gsz) {   // W0p <- Whh0^T
        int n = i >> 7, k = (i & 127) * 4;
        int lo = __builtin_amdgcn_cvt_pk_fp8_f32(Whh0[(size_t)(k+0)*2048+n], Whh0[(size_t)(k+1)*2048+n], 0, false);
        int pk = __builtin_amdgcn_cvt_pk_fp8_f32(Whh0[(size_t)(k+2)*2048+n], Whh0[(size_t)(k+3)*2048+n], lo, true);
        int nb = n >> 4;
        int q = ((nb >> 5) << 2) + (nb & 3);
        size_t dst = (((size_t)(k >> 5) * 8 + ((nb >> 2) & 7)) * 8 + (q >> 1)) * 1024
                   + ((k >> 3) & 3) * 256 + (n & 15) * 16 + (q & 1) * 8 + (k & 4);
        *(int*)(W0p + dst) = pk;
    }
    for (size_t i = tid; i < 2048ull * 1024 / 4; i += gsz) {  // W1p <- [Wih1;Whh1]^T
        int n = i >> 8, k = (i & 255) * 4;
        float f0, f1, f2, f3;
        if (k < 512) {
            f0 = Wih1[(size_t)(k+0)*2048+n]; f1 = Wih1[(size_t)(k+1)*2048+n];
            f2 = Wih1[(size_t)(k+2)*2048+n]; f3 = Wih1[(size_t)(k+3)*2048+n];
        } else {
            int kk = k - 512;
            f0 = Whh1[(size_t)(kk+0)*2048+n]; f1 = Whh1[(size_t)(kk+1)*2048+n];
            f2 = Whh1[(size_t)(kk+2)*2048+n]; f3 = Whh1[(size_t)(kk+3)*2048+n];
        }
        int lo = __builtin_amdgcn_cvt_pk_fp8_f32(f0, f1, 0, false);
        int pk = __builtin_amdgcn_cvt_pk_fp8_f32(f2, f3, lo, true);
        int nb = n >> 4;
        int q = ((nb >> 5) << 2) + (nb & 3);
        size_t dst = (((size_t)(k >> 5) * 8 + ((nb >> 2) & 7)) * 8 + (q >> 1)) * 1024
                   + ((k >> 3) & 3) * 256 + (n & 15) * 16 + (q & 1) * 8 + (k & 4);
        *(int*)(W1p + dst) = pk;
    }
    for (size_t i = tid; i < 32ull * 512 / 4; i += gsz) {     // Wo1p/Wg1p (N=32, nb*16+kt, b64 layout)
        int n = i >> 7, k = (i & 127) * 4;
        size_t dst = ((size_t)(n >> 4) * 16 + (k >> 5)) * 512 + ((k >> 3) & 3) * 128 + (n & 15) * 8 + (k & 4);
        int lo = __builtin_amdgcn_cvt_pk_fp8_f32(Wo1[(size_t)(k+0)*32+n], Wo1[(size_t)(k+1)*32+n], 0, false);
        int pk = __builtin_amdgcn_cvt_pk_fp8_f32(Wo1[(size_t)(k+2)*32+n], Wo1[(size_t)(k+3)*32+n], lo, true);
        *(int*)(Wo1p + dst) = pk;
        lo = __builtin_amdgcn_cvt_pk_fp8_f32(Wg1[(size_t)(k+0)*32+n], Wg1[(size_t)(k+1)*32+n], 0, false);
        pk = __builtin_amdgcn_cvt_pk_fp8_f32(Wg1[(size_t)(k+2)*32+n], Wg1[(size_t)(k+3)*32+n], lo, true);
        *(int*)(Wg1p + dst) = pk;
    }
    for (size_t i = tid; i < 4096ull * 256; i += gsz) {       // Wit[n][k] bf16
        size_t n = i >> 8, k = i & 255;
        float v = (n < 1024) ? Whi[k * 1024 + n]
                : (n < 2048) ? Wci[k * 1024 + (n - 1024)]
                             : Wih0[(1 + k) * 2048 + (n - 2048)];
        Wit[i] = __float2bfloat16(v);
    }
}

// ---------------------------------------------------------------------------
// Init GEMM (bf16): h stored fp8 plain [b][512], c f32, ctxg bf16 [b][j][4g].
// ---------------------------------------------------------------------------
__global__ void __launch_bounds__(256)
k_init(const bf16* __restrict__ efb, const bf16* __restrict__ ctxb,
       const bf16* __restrict__ Wit,
       const float* __restrict__ bh,  const float* __restrict__ bc,
       const float* __restrict__ bi0, const float* __restrict__ bh0,
       u8* __restrict__ h0, u8* __restrict__ h1,
       float* __restrict__ c0, float* __restrict__ c1,
       bf16* __restrict__ ctxg)
{
    const int t = threadIdx.x, lane = t & 63, w = t >> 6;
    const int wr = w >> 1, wc = w & 1;
    const int lq = lane >> 4, ln = lane & 15;
    const int m0 = blockIdx.x * 128, n0 = blockIdx.y * 64;
    const bf16* A = (n0 < 2048) ? efb : ctxb;

    f32x4 zero = {0.f, 0.f, 0.f, 0.f};
    f32x4 acc[4][2];
#pragma unroll
    for (int r = 0; r < 4; ++r)
#pragma unroll
        for (int c = 0; c < 2; ++c) acc[r][c] = zero;

    for (int k0 = 0; k0 < 256; k0 += 32) {
        short8 af[4];
#pragma unroll
        for (int r = 0; r < 4; ++r)
            af[r] = *(const short8*)(A + (size_t)(m0 + wr * 64 + r * 16 + ln) * 256 + k0 + lq * 8);
#pragma unroll
        for (int c = 0; c < 2; ++c) {
            short8 bv = *(const short8*)(Wit + (size_t)(n0 + wc * 32 + c * 16 + ln) * 256 + k0 + lq * 8);
#pragma unroll
            for (int r = 0; r < 4; ++r)
                acc[r][c] = __builtin_amdgcn_mfma_f32_16x16x32_bf16(af[r], bv, acc[r][c], 0, 0, 0);
        }
    }
#pragma unroll
    for (int r = 0; r < 4; ++r)
#pragma unroll
        for (int c = 0; c < 2; ++c)
#pragma unroll
            for (int e = 0; e < 4; ++e) {
                int b = m0 + wr * 64 + r * 16 + lq * 4 + e;
                int n = n0 + wc * 32 + c * 16 + ln;
                float v = acc[r][c][e];
                if (n < 1024) {
                    v += bh[n];
                    if (n < 512) h0[(size_t)b * 512 + n]       = f2fp8(v);
                    else         h1[(size_t)b * 512 + n - 512] = f2fp8(v);
                } else if (n < 2048) {
                    int m = n - 1024; v += bc[m];
                    if (m < 512) c0[(size_t)b * 512 + m]       = v;
                    else         c1[(size_t)b * 512 + m - 512] = v;
                } else {
                    int j = n - 2048;
                    ctxg[(size_t)b * 2048 + (j & 511) * 4 + (j >> 9)] =
                        __float2bfloat16(v + bi0[j] + bh0[j]);
                }
            }
}

// h-LDS B-frag read (B[k][b=ln]): row=ln, chunk c=4kt+lq, swizzle c^ln (4-bit)
__device__ __forceinline__ long hread(const u8* buf, int ln, int lq, int kt) {
    int c = (kt << 2) + lq;
    return *(const long*)(buf + ln * 512 + ((c ^ ln) << 3));
}

// stage one 2 KB quarter-kt (global quarter qq) into the given ring slot
__device__ __forceinline__ void stageQ(const u8* __restrict__ Wp, int w, int qq,
                                       u8* slot, int lane) {
    const u8* src = Wp + (((size_t)(qq >> 2) * 8 + w) << 13) + ((size_t)(qq & 3) << 11) + lane * 16;
    gload16(src,        slot + lane * 16);
    gload16(src + 1024, slot + 1024 + lane * 16);
}

// consume one quarter: 2 ds_read_b128 -> 4 frags -> 8 MFMA (4 per tile)
template <int QT>
__device__ __forceinline__ void mfmaQ(const u8* slot, int lane, long bf0, long bf1,
                                      f32x4 (&a0)[4][4], f32x4 (&a1)[4][4]) {
    lx2 v0 = *(const lx2*)(slot + lane * 16);
    lx2 v1 = *(const lx2*)(slot + 1024 + lane * 16);
#pragma unroll
    for (int i = 0; i < 4; ++i) {
        constexpr int dummy = 0; (void)dummy;
    }
    constexpr int q0 = 4 * QT;
    a0[(q0 + 0) & 3][(q0 + 0) >> 2] = __builtin_amdgcn_mfma_f32_16x16x32_fp8_fp8(v0[0], bf0, a0[(q0 + 0) & 3][(q0 + 0) >> 2], 0, 0, 0);
    a1[(q0 + 0) & 3][(q0 + 0) >> 2] = __builtin_amdgcn_mfma_f32_16x16x32_fp8_fp8(v0[0], bf1, a1[(q0 + 0) & 3][(q0 + 0) >> 2], 0, 0, 0);
    a0[(q0 + 1) & 3][(q0 + 1) >> 2] = __builtin_amdgcn_mfma_f32_16x16x32_fp8_fp8(v0[1], bf0, a0[(q0 + 1) & 3][(q0 + 1) >> 2], 0, 0, 0);
    a1[(q0 + 1) & 3][(q0 + 1) >> 2] = __builtin_amdgcn_mfma_f32_16x16x32_fp8_fp8(v0[1], bf1, a1[(q0 + 1) & 3][(q0 + 1) >> 2], 0, 0, 0);
    a0[(q0 + 2) & 3][(q0 + 2) >> 2] = __builtin_amdgcn_mfma_f32_16x16x32_fp8_fp8(v1[0], bf0, a0[(q0 + 2) & 3][(q0 + 2) >> 2], 0, 0, 0);
    a1[(q0 + 2) & 3][(q0 + 2) >> 2] = __builtin_amdgcn_mfma_f32_16x16x32_fp8_fp8(v1[0], bf1, a1[(q0 + 2) & 3][(q0 + 2) >> 2], 0, 0, 0);
    a0[(q0 + 3) & 3][(q0 + 3) >> 2] = __builtin_amdgcn_mfma_f32_16x16x32_fp8_fp8(v1[1], bf0, a0[(q0 + 3) & 3][(q0 + 3) >> 2], 0, 0, 0);
    a1[(q0 + 3) & 3][(q0 + 3) >> 2] = __builtin_amdgcn_mfma_f32_16x16x32_fp8_fp8(v1[1], bf1, a1[(q0 + 3) & 3][(q0 + 3) >> 2], 0, 0, 0);
}

// ---------------------------------------------------------------------------
// Persistent T-loop kernel, 2-TILE: 128 WGs x 512 thr; WG owns 32 rows as
// two 16-row tiles. Each staged weight fragment feeds 2 MFMA (one per tile)
// -> weight + LDS traffic per unit work HALVED vs R16. Per-wave ring-4 of
// 2 KB quarter-kt slots (slot = qt, statically), counted vmcnt(4), seamless
// across layer/step boundaries. Persistent arch regs: c-state only (64);
// ctxg streamed just-in-time per epilogue tile.
// ---------------------------------------------------------------------------
__global__ void __launch_bounds__(512, 1)
k_loop(const u8* __restrict__ h0i, const u8* __restrict__ h1i,
       const u8* __restrict__ W0p, const u8* __restrict__ W1p,
       const u8* __restrict__ Wo1p, const u8* __restrict__ Wg1p,
       const bf16* __restrict__ ctxg, const float* __restrict__ ii,
       const float* __restrict__ w0row,
       const float* __restrict__ bi1, const float* __restrict__ bh1,
       const float* __restrict__ bo1, const float* __restrict__ Wo2,
       const float* __restrict__ bo2,
       const float* __restrict__ bg1, const float* __restrict__ Wg2,
       const float* __restrict__ bg2,
       const float* __restrict__ c0g, const float* __restrict__ c1g,
       float* __restrict__ out)
{
    __shared__ u8 h0L[2][8192];
    __shared__ u8 h1L[2][8192];
    __shared__ u8 Wring[8][4][2048];         // 64 KB: per-wave ring-4 x 2 KB
    __shared__ unsigned short a0Lb[2048];    // w0row as bf16
    __shared__ unsigned short a1Lb[2048];    // bi1+bh1 as bf16
    __shared__ float sit[2][16];
    __shared__ float spart[2][16][2];

    const int t = threadIdx.x, lane = t & 63, w = t >> 6;
    const int ln = lane & 15, lq = lane >> 4;
    const int m0 = blockIdx.x * 32;
    f32x4 zero = {0.f, 0.f, 0.f, 0.f};

    // ---- prologue: h-init (both tiles) -> LDS swizzled; biases -> LDS bf16
#pragma unroll
    for (int i = 0; i < 4; ++i) {
        int cid = i * 512 + t;
        int row = cid >> 6, c = cid & 63;        // row 0..31
        int tl = row >> 4, r = row & 15;
        long v0 = *(const long*)(h0i + (size_t)(m0 + row) * 512 + c * 8);
        long v1 = *(const long*)(h1i + (size_t)(m0 + row) * 512 + c * 8);
        int pc = r * 512 + ((c ^ r) << 3);
        *(long*)(&h0L[tl][pc]) = v0;
        *(long*)(&h1L[tl][pc]) = v1;
    }
#pragma unroll
    for (int i = 0; i < 4; ++i) {
        int idx = i * 512 + t;
        a0Lb[idx] = (unsigned short)(__bfloat16_as_ushort(__float2bfloat16(w0row[idx])));
        a1Lb[idx] = (unsigned short)(__bfloat16_as_ushort(__float2bfloat16(bi1[idx] + bh1[idx])));
    }
    // ---- per-thread resident c-state for both tiles (64 VGPRs)
    f32x4 cr0[2][4], cr1[2][4];
#pragma unroll
    for (int tl = 0; tl < 2; ++tl) {
        int bb = m0 + 16 * tl + ln;
#pragma unroll
        for (int jc = 0; jc < 4; ++jc) {
            int jlb = (w * 4 + jc) * 16 + lq * 4;
            cr0[tl][jc] = *(const f32x4*)(c0g + (size_t)bb * 512 + jlb);
            cr1[tl][jc] = *(const f32x4*)(c1g + (size_t)bb * 512 + jlb);
        }
    }
    __syncthreads();

    // intent head: waves 0,1 -> tile0; waves 2,3 -> tile1 (16 cols per wave)
    auto head2 = [&](const u8* Wp, const float* b1, const float* W2, float b2s,
                     bool tosit, float* dst, int stride, int scol) {
        if (w < 4) {
            int tl = w >> 1, wh = w & 1;
            const u8* hb = h1L[tl];
            f32x4 acc = zero;
#pragma unroll
            for (int kt = 0; kt < 16; ++kt) {
                long bf = hread(hb, ln, lq, kt);
                long af = *(const long*)(Wp + (size_t)(wh * 16 + kt) * 512 + lane * 8);
                acc = __builtin_amdgcn_mfma_f32_16x16x32_fp8_fp8(af, bf, acc, 0, 0, 0);
            }
            float v = 0.f;
#pragma unroll
            for (int e = 0; e < 4; ++e) {
                int j = wh * 16 + lq * 4 + e;
                v += fmaxf(acc[e] + b1[j], 0.f) * W2[j];
            }
            v += __shfl_xor(v, 16);
            v += __shfl_xor(v, 32);
            if (lq == 0) spart[tl][ln][wh] = v;
        }
        __syncthreads();
        if (t < 32) {
            int tl = t >> 4, r = t & 15;
            float pv = sigf(spart[tl][r][0] + spart[tl][r][1] + b2s);
            if (tosit) sit[tl][r] = pv;
            if (dst) dst[(size_t)(m0 + 16 * tl + r) * stride + scol] = pv;
        }
        __syncthreads();
    };

    u8* S0 = Wring[w][0];
    u8* S1 = Wring[w][1];
    u8* S2 = Wring[w][2];
    u8* S3 = Wring[w][3];

    // seed the ring for step 0's layer 0 (quarters 0,1,2 in flight)
    stageQ(W0p, w, 0, S0, lane);
    stageQ(W0p, w, 1, S1, lane);
    stageQ(W0p, w, 2, S2, lane);

    for (int s = 0; s < Tsz; ++s) {
        if (s == 0) {
            if (t < 32) sit[t >> 4][t & 15] = ii[m0 + t];
            __syncthreads();
        } else {
            head2(Wo1p, bo1, Wo2, bo2[0], true, out, Tsz, s - 1);
        }
        const float sv0 = sit[0][ln], sv1 = sit[1][ln];

        // ================= layer 0: K=512 (16 kt x 4 quarters) =============
        {
            f32x4 a0[4][4], a1[4][4];
#pragma unroll
            for (int jc = 0; jc < 4; ++jc)
#pragma unroll
                for (int g = 0; g < 4; ++g) { a0[jc][g] = zero; a1[jc][g] = zero; }

            for (int kt = 0; kt < 15; ++kt) {
                long bf0 = hread(h0L[0], ln, lq, kt);
                long bf1 = hread(h0L[1], ln, lq, kt);
                int qq = kt * 4;
                WAIT_VM(4); mfmaQ<0>(S0, lane, bf0, bf1, a0, a1); stageQ(W0p, w, qq + 3, S3, lane);
                WAIT_VM(4); mfmaQ<1>(S1, lane, bf0, bf1, a0, a1); stageQ(W0p, w, qq + 4, S0, lane);
                WAIT_VM(4); mfmaQ<2>(S2, lane, bf0, bf1, a0, a1); stageQ(W0p, w, qq + 5, S1, lane);
                WAIT_VM(4); mfmaQ<3>(S3, lane, bf0, bf1, a0, a1); stageQ(W0p, w, qq + 6, S2, lane);
            }
            {   // kt = 15: tail pre-stages layer-1 quarters 0..2
                long bf0 = hread(h0L[0], ln, lq, 15);
                long bf1 = hread(h0L[1], ln, lq, 15);
                WAIT_VM(4); mfmaQ<0>(S0, lane, bf0, bf1, a0, a1); stageQ(W0p, w, 63, S3, lane);
                WAIT_VM(4); mfmaQ<1>(S1, lane, bf0, bf1, a0, a1); stageQ(W1p, w, 0, S0, lane);
                WAIT_VM(4); mfmaQ<2>(S2, lane, bf0, bf1, a0, a1); stageQ(W1p, w, 1, S1, lane);
                WAIT_VM(4); mfmaQ<3>(S3, lane, bf0, bf1, a0, a1); stageQ(W1p, w, 2, S2, lane);
            }
            // epilogue (per tile): ctxg just-in-time, cell, pack h0 bytes
            int hold[2][4];
#pragma unroll
            for (int tl = 0; tl < 2; ++tl) {
                int bb = m0 + 16 * tl + ln;
                const float sval = tl ? sv1 : sv0;
                f32x4* cr = cr0[tl];
                f32x4 (&acc)[4][4] = tl ? a1 : a0;
#pragma unroll
                for (int jc = 0; jc < 4; ++jc) {
                    int jlb = (w * 4 + jc) * 16 + lq * 4;
                    us4 a0v[4];
#pragma unroll
                    for (int g = 0; g < 4; ++g) a0v[g] = *(const us4*)(a0Lb + g * 512 + jlb);
                    float hv[4];
#pragma unroll
                    for (int e = 0; e < 4; ++e) {
                        us4 xgv = *(const us4*)((const unsigned short*)ctxg + (size_t)bb * 2048 + (jlb + e) * 4);
                        float pre[4];
#pragma unroll
                        for (int g = 0; g < 4; ++g)
                            pre[g] = acc[jc][g][e] + b2f(xgv[g]) + sval * b2f(a0v[g][e]);
                        float ig = sigf(pre[0]), fg = sigf(pre[1]);
                        float gg = tanhft(pre[2]), og = sigf(pre[3]);
                        float cn = fg * cr[jc][e] + ig * gg;
                        cr[jc][e] = cn;
                        hv[e] = og * tanhft(cn);
                    }
                    int lo = __builtin_amdgcn_cvt_pk_fp8_f32(hv[0], hv[1], 0, false);
                    hold[tl][jc] = __builtin_amdgcn_cvt_pk_fp8_f32(hv[2], hv[3], lo, true);
                }
            }
            __syncthreads();                          // all done reading h0L
#pragma unroll
            for (int tl = 0; tl < 2; ++tl)
#pragma unroll
                for (int jc = 0; jc < 4; ++jc) {
                    int c = (w * 4 + jc) * 2 + (lq >> 1);
                    *(int*)(h0L[tl] + ln * 512 + ((c ^ ln) << 3) + (lq & 1) * 4) = hold[tl][jc];
                }
            asm volatile("s_waitcnt lgkmcnt(0)" ::: "memory");
            __syncthreads();                          // h0 new visible
        }

        // ====== layer 1: K=1024 (32 kt); kt<16 from h0L, else h1L =========
        {
            f32x4 a0[4][4], a1[4][4];
#pragma unroll
            for (int jc = 0; jc < 4; ++jc)
#pragma unroll
                for (int g = 0; g < 4; ++g) { a0[jc][g] = zero; a1[jc][g] = zero; }

            for (int kt = 0; kt < 16; ++kt) {
                long bf0 = hread(h0L[0], ln, lq, kt);
                long bf1 = hread(h0L[1], ln, lq, kt);
                int qq = kt * 4;
                WAIT_VM(4); mfmaQ<0>(S0, lane, bf0, bf1, a0, a1); stageQ(W1p, w, qq + 3, S3, lane);
                WAIT_VM(4); mfmaQ<1>(S1, lane, bf0, bf1, a0, a1); stageQ(W1p, w, qq + 4, S0, lane);
                WAIT_VM(4); mfmaQ<2>(S2, lane, bf0, bf1, a0, a1); stageQ(W1p, w, qq + 5, S1, lane);
                WAIT_VM(4); mfmaQ<3>(S3, lane, bf0, bf1, a0, a1); stageQ(W1p, w, qq + 6, S2, lane);
            }
            for (int kt = 16; kt < 31; ++kt) {
                long bf0 = hread(h1L[0], ln, lq, kt - 16);
                long bf1 = hread(h1L[1], ln, lq, kt - 16);
                int qq = kt * 4;
                WAIT_VM(4); mfmaQ<0>(S0, lane, bf0, bf1, a0, a1); stageQ(W1p, w, qq + 3, S3, lane);
                WAIT_VM(4); mfmaQ<1>(S1, lane, bf0, bf1, a0, a1); stageQ(W1p, w, qq + 4, S0, lane);
                WAIT_VM(4); mfmaQ<2>(S2, lane, bf0, bf1, a0, a1); stageQ(W1p, w, qq + 5, S1, lane);
                WAIT_VM(4); mfmaQ<3>(S3, lane, bf0, bf1, a0, a1); stageQ(W1p, w, qq + 6, S2, lane);
            }
            {   // kt = 31: tail pre-stages next step's layer-0 quarters 0..2
                long bf0 = hread(h1L[0], ln, lq, 15);
                long bf1 = hread(h1L[1], ln, lq, 15);
                WAIT_VM(4); mfmaQ<0>(S0, lane, bf0, bf1, a0, a1); stageQ(W1p, w, 127, S3, lane);
                WAIT_VM(4); mfmaQ<1>(S1, lane, bf0, bf1, a0, a1); stageQ(W0p, w, 0, S0, lane);
                WAIT_VM(4); mfmaQ<2>(S2, lane, bf0, bf1, a0, a1); stageQ(W0p, w, 1, S1, lane);
                WAIT_VM(4); mfmaQ<3>(S3, lane, bf0, bf1, a0, a1); stageQ(W0p, w, 2, S2, lane);
            }
            int hold[2][4];
#pragma unroll
            for (int tl = 0; tl < 2; ++tl) {
                f32x4* cr = cr1[tl];
                f32x4 (&acc)[4][4] = tl ? a1 : a0;
#pragma unroll
                for (int jc = 0; jc < 4; ++jc) {
                    int jlb = (w * 4 + jc) * 16 + lq * 4;
                    us4 a1v[4];
#pragma unroll
                    for (int g = 0; g < 4; ++g) a1v[g] = *(const us4*)(a1Lb + g * 512 + jlb);
                    float hv[4];
#pragma unroll
                    for (int e = 0; e < 4; ++e) {
                        float pre[4];
#pragma unroll
                        for (int g = 0; g < 4; ++g) pre[g] = acc[jc][g][e] + b2f(a1v[g][e]);
                        float ig = sigf(pre[0]), fg = sigf(pre[1]);
                        float gg = tanhft(pre[2]), og = sigf(pre[3]);
                        float cn = fg * cr[jc][e] + ig * gg;
                        cr[jc][e] = cn;
                        hv[e] = og * tanhft(cn);
                    }
                    int lo = __builtin_amdgcn_cvt_pk_fp8_f32(hv[0], hv[1], 0, false);
                    hold[tl][jc] = __builtin_amdgcn_cvt_pk_fp8_f32(hv[2], hv[3], lo, true);
                }
            }
            __syncthreads();                          // all done reading h1L
#pragma unroll
            for (int tl = 0; tl < 2; ++tl)
#pragma unroll
                for (int jc = 0; jc < 4; ++jc) {
                    int c = (w * 4 + jc) * 2 + (lq >> 1);
                    *(int*)(h1L[tl] + ln * 512 + ((c ^ ln) << 3) + (lq & 1) * 4) = hold[tl][jc];
                }
            asm volatile("s_waitcnt lgkmcnt(0)" ::: "memory");
            __syncthreads();                          // h1 new visible
        }
    }

    // ---- final heads on the final h1; stray in-flight stage loads benign
    head2(Wo1p, bo1, Wo2, bo2[0], false, out, Tsz, 44);
    head2(Wg1p, bg1, Wg2, bg2[0], false, out + (size_t)Bsz * Tsz, 1, 0);
}

// ---------------------------------------------------------------------------
extern "C" void kernel_launch(void* const* d_in, const int* in_sizes, int n_in,
                              void* d_out, int out_size, void* d_ws, size_t ws_size,
                              hipStream_t stream)
{
    const float* ef   = (const float*)d_in[0];
    const float* ctx  = (const float*)d_in[1];
    const float* ii   = (const float*)d_in[2];
    const float* Whi  = (const float*)d_in[3];
    const float* bh   = (const float*)d_in[4];
    const float* Wci  = (const float*)d_in[5];
    const float* bc   = (const float*)d_in[6];
    const float* Wih0 = (const float*)d_in[7];
    const float* Whh0 = (const float*)d_in[8];
    const float* bi0  = (const float*)d_in[9];
    const float* bh0  = (const float*)d_in[10];
    const float* Wih1 = (const float*)d_in[11];
    const float* Whh1 = (const float*)d_in[12];
    const float* bi1  = (const float*)d_in[13];
    const float* bh1  = (const float*)d_in[14];
    const float* Wo1  = (const float*)d_in[15];
    const float* bo1  = (const float*)d_in[16];
    const float* Wo2  = (const float*)d_in[17];
    const float* bo2  = (const float*)d_in[18];
    const float* Wg1  = (const float*)d_in[19];
    const float* bg1  = (const float*)d_in[20];
    const float* Wg2  = (const float*)d_in[21];
    const float* bg2  = (const float*)d_in[22];
    float* out = (float*)d_out;

    char* ws = (char*)d_ws;
    size_t off = 0;
    auto take = [&](size_t bytes) -> char* {
        char* pp = ws + off;
        off += (bytes + 255) & ~(size_t)255;
        return pp;
    };
    u8*  W0p     = (u8*)take(2048ull * 512);
    u8*  W1p     = (u8*)take(2048ull * 1024);
    u8*  Wo1p    = (u8*)take(32ull * 512);
    u8*  Wg1p    = (u8*)take(32ull * 512);
    bf16* Wit    = (bf16*)take(4096ull * 256 * 2);
    bf16* efb    = (bf16*)take((size_t)Bsz * Dsz * 2);
    bf16* ctxb   = (bf16*)take((size_t)Bsz * Dsz * 2);
    u8*  h0x     = (u8*)take((size_t)Bsz * Hsz);
    u8*  h1x     = (u8*)take((size_t)Bsz * Hsz);
    float* c0    = (float*)take((size_t)Bsz * Hsz * 4);
    float* c1    = (float*)take((size_t)Bsz * Hsz * 4);
    bf16* ctxg   = (bf16*)take((size_t)Bsz * 2048 * 2);
    (void)ws_size; (void)in_sizes; (void)n_in; (void)out_size;

    k_conv<<<2048, 256, 0, stream>>>(ef, ctx, Whi, Wci, Wih0, Whh0, Wih1, Whh1, Wo1, Wg1,
                                     efb, ctxb, Wit, W0p, W1p, Wo1p, Wg1p);
    k_init<<<dim3(32, 64), 256, 0, stream>>>(efb, ctxb, Wit, bh, bc, bi0, bh0,
                                             h0x, h1x, c0, c1, ctxg);
    k_loop<<<128, 512, 0, stream>>>(h0x, h1x, W0p, W1p, Wo1p, Wg1p,
                                    ctxg, ii, Wih0, bi1, bh1,
                                    bo1, Wo2, bo2, bg1, Wg2, bg2,
                                    c0, c1, out);
}

// Round 19
// 2402.424 us; speedup vs baseline: 1.5185x; 1.3369x over previous
//
#include <hip/hip_runtime.h>
#include <hip/hip_bf16.h>

#define Bsz 4096
#define Dsz 256
#define Hsz 512
#define Tsz 45

typedef __attribute__((ext_vector_type(8))) short short8;
typedef __attribute__((ext_vector_type(4))) float f32x4;
typedef __attribute__((ext_vector_type(4))) unsigned short us4;
typedef __attribute__((ext_vector_type(2))) long lx2;
using bf16 = __hip_bfloat16;
using u8 = unsigned char;

__device__ __forceinline__ float sigf(float x)   { return 1.0f / (1.0f + __expf(-x)); }
__device__ __forceinline__ float tanhft(float x) { return 1.0f - 2.0f / (__expf(2.0f * x) + 1.0f); }
__device__ __forceinline__ float b2f(unsigned short u) { return __uint_as_float((unsigned)u << 16); }
__device__ __forceinline__ u8 f2fp8(float v) {
    int p = __builtin_amdgcn_cvt_pk_fp8_f32(v, v, 0, false);
    return (u8)(p & 0xff);
}

__device__ __forceinline__ void gload16(const void* g, void* l) {
    __builtin_amdgcn_global_load_lds((const __attribute__((address_space(1))) void*)g,
                                     (__attribute__((address_space(3))) void*)l, 16, 0, 0);
}

#define WAIT_VM(N) asm volatile("s_waitcnt vmcnt(" #N ")" ::: "memory")

// ---------------------------------------------------------------------------
// Weight convert/pack (one-shot, byte-identical to R16 — proven numerics).
// PAIR-PACKED fragment blocks: per (kt,wave) the 16 frags live as 8 x 1 KB
// pair-blocks; pair p holds frag 2p in lane bytes [0:8) and 2p+1 in [8:16).
// ---------------------------------------------------------------------------
__global__ void k_conv(const float* __restrict__ ef,   const float* __restrict__ ctx,
                       const float* __restrict__ Whi,  const float* __restrict__ Wci,
                       const float* __restrict__ Wih0, const float* __restrict__ Whh0,
                       const float* __restrict__ Wih1, const float* __restrict__ Whh1,
                       const float* __restrict__ Wo1,  const float* __restrict__ Wg1,
                       bf16* __restrict__ efb,  bf16* __restrict__ ctxb,
                       bf16* __restrict__ Wit,  u8* __restrict__ W0p,
                       u8* __restrict__ W1p,  u8* __restrict__ Wo1p,
                       u8* __restrict__ Wg1p)
{
    size_t tid = (size_t)blockIdx.x * blockDim.x + threadIdx.x;
    size_t gsz = (size_t)gridDim.x * blockDim.x;
    for (size_t i = tid; i < (size_t)Bsz * Dsz; i += gsz) {
        efb[i]  = __float2bfloat16(ef[i]);
        ctxb[i] = __float2bfloat16(ctx[i]);
    }
    for (size_t i = tid; i < 2048ull * 512 / 4; i += gsz) {   // W0p <- Whh0^T
        int n = i >> 7, k = (i & 127) * 4;
        int lo = __builtin_amdgcn_cvt_pk_fp8_f32(Whh0[(size_t)(k+0)*2048+n], Whh0[(size_t)(k+1)*2048+n], 0, false);
        int pk = __builtin_amdgcn_cvt_pk_fp8_f32(Whh0[(size_t)(k+2)*2048+n], Whh0[(size_t)(k+3)*2048+n], lo, true);
        int nb = n >> 4;
        int q = ((nb >> 5) << 2) + (nb & 3);
        size_t dst = (((size_t)(k >> 5) * 8 + ((nb >> 2) & 7)) * 8 + (q >> 1)) * 1024
                   + ((k >> 3) & 3) * 256 + (n & 15) * 16 + (q & 1) * 8 + (k & 4);
        *(int*)(W0p + dst) = pk;
    }
    for (size_t i = tid; i < 2048ull * 1024 / 4; i += gsz) {  // W1p <- [Wih1;Whh1]^T
        int n = i >> 8, k = (i & 255) * 4;
        float f0, f1, f2, f3;
        if (k < 512) {
            f0 = Wih1[(size_t)(k+0)*2048+n]; f1 = Wih1[(size_t)(k+1)*2048+n];
            f2 = Wih1[(size_t)(k+2)*2048+n]; f3 = Wih1[(size_t)(k+3)*2048+n];
        } else {
            int kk = k - 512;
            f0 = Whh1[(size_t)(kk+0)*2048+n]; f1 = Whh1[(size_t)(kk+1)*2048+n];
            f2 = Whh1[(size_t)(kk+2)*2048+n]; f3 = Whh1[(size_t)(kk+3)*2048+n];
        }
        int lo = __builtin_amdgcn_cvt_pk_fp8_f32(f0, f1, 0, false);
        int pk = __builtin_amdgcn_cvt_pk_fp8_f32(f2, f3, lo, true);
        int nb = n >> 4;
        int q = ((nb >> 5) << 2) + (nb & 3);
        size_t dst = (((size_t)(k >> 5) * 8 + ((nb >> 2) & 7)) * 8 + (q >> 1)) * 1024
                   + ((k >> 3) & 3) * 256 + (n & 15) * 16 + (q & 1) * 8 + (k & 4);
        *(int*)(W1p + dst) = pk;
    }
    for (size_t i = tid; i < 32ull * 512 / 4; i += gsz) {     // Wo1p/Wg1p (N=32, nb*16+kt, b64 layout)
        int n = i >> 7, k = (i & 127) * 4;
        size_t dst = ((size_t)(n >> 4) * 16 + (k >> 5)) * 512 + ((k >> 3) & 3) * 128 + (n & 15) * 8 + (k & 4);
        int lo = __builtin_amdgcn_cvt_pk_fp8_f32(Wo1[(size_t)(k+0)*32+n], Wo1[(size_t)(k+1)*32+n], 0, false);
        int pk = __builtin_amdgcn_cvt_pk_fp8_f32(Wo1[(size_t)(k+2)*32+n], Wo1[(size_t)(k+3)*32+n], lo, true);
        *(int*)(Wo1p + dst) = pk;
        lo = __builtin_amdgcn_cvt_pk_fp8_f32(Wg1[(size_t)(k+0)*32+n], Wg1[(size_t)(k+1)*32+n], 0, false);
        pk = __builtin_amdgcn_cvt_pk_fp8_f32(Wg1[(size_t)(k+2)*32+n], Wg1[(size_t)(k+3)*32+n], lo, true);
        *(int*)(Wg1p + dst) = pk;
    }
    for (size_t i = tid; i < 4096ull * 256; i += gsz) {       // Wit[n][k] bf16
        size_t n = i >> 8, k = i & 255;
        float v = (n < 1024) ? Whi[k * 1024 + n]
                : (n < 2048) ? Wci[k * 1024 + (n - 1024)]
                             : Wih0[(1 + k) * 2048 + (n - 2048)];
        Wit[i] = __float2bfloat16(v);
    }
}

// ---------------------------------------------------------------------------
// Init GEMM (bf16): h stored fp8 plain [b][512], c f32, ctxg bf16 [b][j][4g].
// ---------------------------------------------------------------------------
__global__ void __launch_bounds__(256)
k_init(const bf16* __restrict__ efb, const bf16* __restrict__ ctxb,
       const bf16* __restrict__ Wit,
       const float* __restrict__ bh,  const float* __restrict__ bc,
       const float* __restrict__ bi0, const float* __restrict__ bh0,
       u8* __restrict__ h0, u8* __restrict__ h1,
       float* __restrict__ c0, float* __restrict__ c1,
       bf16* __restrict__ ctxg)
{
    const int t = threadIdx.x, lane = t & 63, w = t >> 6;
    const int wr = w >> 1, wc = w & 1;
    const int lq = lane >> 4, ln = lane & 15;
    const int m0 = blockIdx.x * 128, n0 = blockIdx.y * 64;
    const bf16* A = (n0 < 2048) ? efb : ctxb;

    f32x4 zero = {0.f, 0.f, 0.f, 0.f};
    f32x4 acc[4][2];
#pragma unroll
    for (int r = 0; r < 4; ++r)
#pragma unroll
        for (int c = 0; c < 2; ++c) acc[r][c] = zero;

    for (int k0 = 0; k0 < 256; k0 += 32) {
        short8 af[4];
#pragma unroll
        for (int r = 0; r < 4; ++r)
            af[r] = *(const short8*)(A + (size_t)(m0 + wr * 64 + r * 16 + ln) * 256 + k0 + lq * 8);
#pragma unroll
        for (int c = 0; c < 2; ++c) {
            short8 bv = *(const short8*)(Wit + (size_t)(n0 + wc * 32 + c * 16 + ln) * 256 + k0 + lq * 8);
#pragma unroll
            for (int r = 0; r < 4; ++r)
                acc[r][c] = __builtin_amdgcn_mfma_f32_16x16x32_bf16(af[r], bv, acc[r][c], 0, 0, 0);
        }
    }
#pragma unroll
    for (int r = 0; r < 4; ++r)
#pragma unroll
        for (int c = 0; c < 2; ++c)
#pragma unroll
            for (int e = 0; e < 4; ++e) {
                int b = m0 + wr * 64 + r * 16 + lq * 4 + e;
                int n = n0 + wc * 32 + c * 16 + ln;
                float v = acc[r][c][e];
                if (n < 1024) {
                    v += bh[n];
                    if (n < 512) h0[(size_t)b * 512 + n]       = f2fp8(v);
                    else         h1[(size_t)b * 512 + n - 512] = f2fp8(v);
                } else if (n < 2048) {
                    int m = n - 1024; v += bc[m];
                    if (m < 512) c0[(size_t)b * 512 + m]       = v;
                    else         c1[(size_t)b * 512 + m - 512] = v;
                } else {
                    int j = n - 2048;
                    ctxg[(size_t)b * 2048 + (j & 511) * 4 + (j >> 9)] =
                        __float2bfloat16(v + bi0[j] + bh0[j]);
                }
            }
}

// h-LDS B-frag read (B[k][b=ln]): row=ln, chunk c=4kt+lq, swizzle c^ln (4-bit)
__device__ __forceinline__ long hread(const u8* buf, int ln, int lq, int kt) {
    int c = (kt << 2) + lq;
    return *(const long*)(buf + ln * 512 + ((c ^ ln) << 3));
}

// stage one 4 KB half-kt (half h) of the wave's weight stream into ring slot h&3
__device__ __forceinline__ void stageH(const u8* __restrict__ Wp, int w, int h,
                                       u8* Wr, int lane) {
    const u8* src = Wp + ((size_t)((h >> 1) * 8 + w) << 13) + ((size_t)(h & 1) << 12) + lane * 16;
    u8* dst = Wr + ((size_t)(h & 3) << 12);
#pragma unroll
    for (int i = 0; i < 4; ++i)
        gload16(src + i * 1024, dst + i * 1024);
}

// 8 MFMA of one half-kt via 4 x ds_read_b128 (pair-packed frags).
// s_setprio(1) around the MFMA cluster (T5): waves are at different phases
// (private rings, no K-loop barriers) so the CU scheduler can favor the
// MFMA-issuing wave over the staging wave.
template <int QB>
__device__ __forceinline__ void mfma_half(const u8* slot, int lane, long bf,
                                          f32x4 (&acc)[4][4]) {
    lx2 v0 = *(const lx2*)(slot + 0 * 1024 + lane * 16);
    lx2 v1 = *(const lx2*)(slot + 1 * 1024 + lane * 16);
    lx2 v2 = *(const lx2*)(slot + 2 * 1024 + lane * 16);
    lx2 v3 = *(const lx2*)(slot + 3 * 1024 + lane * 16);
    __builtin_amdgcn_s_setprio(1);
    acc[(QB + 0) & 3][(QB + 0) >> 2] = __builtin_amdgcn_mfma_f32_16x16x32_fp8_fp8(v0[0], bf, acc[(QB + 0) & 3][(QB + 0) >> 2], 0, 0, 0);
    acc[(QB + 1) & 3][(QB + 1) >> 2] = __builtin_amdgcn_mfma_f32_16x16x32_fp8_fp8(v0[1], bf, acc[(QB + 1) & 3][(QB + 1) >> 2], 0, 0, 0);
    acc[(QB + 2) & 3][(QB + 2) >> 2] = __builtin_amdgcn_mfma_f32_16x16x32_fp8_fp8(v1[0], bf, acc[(QB + 2) & 3][(QB + 2) >> 2], 0, 0, 0);
    acc[(QB + 3) & 3][(QB + 3) >> 2] = __builtin_amdgcn_mfma_f32_16x16x32_fp8_fp8(v1[1], bf, acc[(QB + 3) & 3][(QB + 3) >> 2], 0, 0, 0);
    acc[(QB + 4) & 3][(QB + 4) >> 2] = __builtin_amdgcn_mfma_f32_16x16x32_fp8_fp8(v2[0], bf, acc[(QB + 4) & 3][(QB + 4) >> 2], 0, 0, 0);
    acc[(QB + 5) & 3][(QB + 5) >> 2] = __builtin_amdgcn_mfma_f32_16x16x32_fp8_fp8(v2[1], bf, acc[(QB + 5) & 3][(QB + 5) >> 2], 0, 0, 0);
    acc[(QB + 6) & 3][(QB + 6) >> 2] = __builtin_amdgcn_mfma_f32_16x16x32_fp8_fp8(v3[0], bf, acc[(QB + 6) & 3][(QB + 6) >> 2], 0, 0, 0);
    acc[(QB + 7) & 3][(QB + 7) >> 2] = __builtin_amdgcn_mfma_f32_16x16x32_fp8_fp8(v3[1], bf, acc[(QB + 7) & 3][(QB + 7) >> 2], 0, 0, 0);
    __builtin_amdgcn_s_setprio(0);
}

// ---------------------------------------------------------------------------
// Persistent T-loop kernel. 256 WGs x 512 thr (16 rows x all 2048 cols/WG).
// Per-wave private ring-4 of 4 KB half-kt slots, counted vmcnt(8), seamless
// ring across layer/step boundaries (no vmcnt(0) in the steady loop).
// All non-weight state resident: ctxg in regs, biases in LDS bf16, c in
// regs, h in LDS. (= R16, the proven 2405 us kernel, + setprio.)
// ---------------------------------------------------------------------------
__global__ void __launch_bounds__(512, 1)
k_loop(const u8* __restrict__ h0i, const u8* __restrict__ h1i,
       const u8* __restrict__ W0p, const u8* __restrict__ W1p,
       const u8* __restrict__ Wo1p, const u8* __restrict__ Wg1p,
       const bf16* __restrict__ ctxg, const float* __restrict__ ii,
       const float* __restrict__ w0row,
       const float* __restrict__ bi1, const float* __restrict__ bh1,
       const float* __restrict__ bo1, const float* __restrict__ Wo2,
       const float* __restrict__ bo2,
       const float* __restrict__ bg1, const float* __restrict__ Wg2,
       const float* __restrict__ bg2,
       const float* __restrict__ c0g, const float* __restrict__ c1g,
       float* __restrict__ out)
{
    __shared__ u8 h0L[8192];
    __shared__ u8 h1L[8192];
    __shared__ u8 WringS[8][16384];          // per-wave ring-4 x 4 KB
    __shared__ unsigned short a0Lb[2048];    // w0row as bf16
    __shared__ unsigned short a1Lb[2048];    // bi1+bh1 as bf16
    __shared__ float sit[16];
    __shared__ float spart[16][2];

    const int t = threadIdx.x, lane = t & 63, w = t >> 6;
    const int ln = lane & 15, lq = lane >> 4;
    const int m0 = blockIdx.x * 16;
    const int b = m0 + ln;
    u8* Wr = WringS[w];
    f32x4 zero = {0.f, 0.f, 0.f, 0.f};

    // ---- prologue: h-init -> LDS (swizzled chunk^row); biases -> LDS bf16
#pragma unroll
    for (int i = 0; i < 2; ++i) {
        int cid = i * 512 + t;
        int row = cid >> 6, c = cid & 63;
        long v0 = *(const long*)(h0i + (size_t)(m0 + row) * 512 + c * 8);
        long v1 = *(const long*)(h1i + (size_t)(m0 + row) * 512 + c * 8);
        int pc = row * 512 + ((c ^ row) << 3);
        *(long*)(&h0L[pc]) = v0;
        *(long*)(&h1L[pc]) = v1;
    }
#pragma unroll
    for (int i = 0; i < 4; ++i) {
        int idx = i * 512 + t;
        a0Lb[idx] = (unsigned short)(__bfloat16_as_ushort(__float2bfloat16(w0row[idx])));
        a1Lb[idx] = (unsigned short)(__bfloat16_as_ushort(__float2bfloat16(bi1[idx] + bh1[idx])));
    }
    // ---- per-thread resident state: c and ctxg at (b=ln, jl=(w*4+jc)*16+lq*4+e)
    f32x4 cr0[4], cr1[4];
    us4 xg[4][4];
#pragma unroll
    for (int jc = 0; jc < 4; ++jc) {
        int jlb = (w * 4 + jc) * 16 + lq * 4;
        cr0[jc] = *(const f32x4*)(c0g + (size_t)b * 512 + jlb);
        cr1[jc] = *(const f32x4*)(c1g + (size_t)b * 512 + jlb);
#pragma unroll
        for (int e = 0; e < 4; ++e)
            xg[jc][e] = *(const us4*)((const unsigned short*)ctxg + (size_t)b * 2048 + (jlb + e) * 4);
    }
    __syncthreads();

    // intent head: waves 0,1 do j-tiles 0,1; all threads call (barriers inside)
    auto head2 = [&](const u8* Wp, const float* b1, const float* W2, float b2s,
                     bool tosit, float* dst, int stride, int scol) {
        if (w < 2) {
            f32x4 acc = zero;
#pragma unroll
            for (int kt = 0; kt < 16; ++kt) {
                long bf = hread(h1L, ln, lq, kt);
                long af = *(const long*)(Wp + (size_t)(w * 16 + kt) * 512 + lane * 8);
                acc = __builtin_amdgcn_mfma_f32_16x16x32_fp8_fp8(af, bf, acc, 0, 0, 0);
            }
            float v = 0.f;
#pragma unroll
            for (int e = 0; e < 4; ++e) {
                int j = w * 16 + lq * 4 + e;
                v += fmaxf(acc[e] + b1[j], 0.f) * W2[j];
            }
            v += __shfl_xor(v, 16);
            v += __shfl_xor(v, 32);
            if (lq == 0) spart[ln][w] = v;
        }
        __syncthreads();
        if (t < 16) {
            float pv = sigf(spart[t][0] + spart[t][1] + b2s);
            if (tosit) sit[t] = pv;
            if (dst) dst[(size_t)(m0 + t) * stride + scol] = pv;
        }
        __syncthreads();
    };

    // seed the ring for step 0's layer 0
    stageH(W0p, w, 0, Wr, lane);
    stageH(W0p, w, 1, Wr, lane);
    stageH(W0p, w, 2, Wr, lane);

    for (int s = 0; s < Tsz; ++s) {
        if (s == 0) {
            if (t < 16) sit[t] = ii[m0 + t];
            __syncthreads();
        } else {
            head2(Wo1p, bo1, Wo2, bo2[0], true, out, Tsz, s - 1);
        }
        const float sval = sit[ln];

        // ================= layer 0: G = W0·h0^T, K=512 (H=32 halves) =======
        {
            f32x4 acc[4][4];
#pragma unroll
            for (int jc = 0; jc < 4; ++jc)
#pragma unroll
                for (int g = 0; g < 4; ++g) acc[jc][g] = zero;

#pragma unroll 2
            for (int kt = 0; kt < 14; ++kt) {
                long bf = hread(h0L, ln, lq, kt);
                WAIT_VM(8);
                mfma_half<0>(Wr + (size_t)((2 * kt) & 3) * 4096, lane, bf, acc);
                stageH(W0p, w, 2 * kt + 3, Wr, lane);
                WAIT_VM(8);
                mfma_half<8>(Wr + (size_t)((2 * kt + 1) & 3) * 4096, lane, bf, acc);
                stageH(W0p, w, 2 * kt + 4, Wr, lane);
            }
            {   // kt = 14: last W0 stage + begin staging layer-1's ring
                long bf = hread(h0L, ln, lq, 14);
                WAIT_VM(8);
                mfma_half<0>(Wr + (size_t)(28 & 3) * 4096, lane, bf, acc);
                stageH(W0p, w, 31, Wr, lane);
                WAIT_VM(8);
                mfma_half<8>(Wr + (size_t)(29 & 3) * 4096, lane, bf, acc);
                stageH(W1p, w, 0, Wr, lane);          // L1 h0 -> slot 0
            }
            {   // kt = 15
                long bf = hread(h0L, ln, lq, 15);
                WAIT_VM(8);
                mfma_half<0>(Wr + (size_t)(30 & 3) * 4096, lane, bf, acc);
                stageH(W1p, w, 1, Wr, lane);          // L1 h1 -> slot 1
                WAIT_VM(8);
                mfma_half<8>(Wr + (size_t)(31 & 3) * 4096, lane, bf, acc);
                stageH(W1p, w, 2, Wr, lane);          // L1 h2 -> slot 2
            }
            // epilogue: cell from resident state only; L1 stages fly meanwhile
            int hold[4];
#pragma unroll
            for (int jc = 0; jc < 4; ++jc) {
                int jlb = (w * 4 + jc) * 16 + lq * 4;
                us4 a0v[4];
#pragma unroll
                for (int g = 0; g < 4; ++g) a0v[g] = *(const us4*)(a0Lb + g * 512 + jlb);
                float hv[4];
#pragma unroll
                for (int e = 0; e < 4; ++e) {
                    float pre[4];
#pragma unroll
                    for (int g = 0; g < 4; ++g)
                        pre[g] = acc[jc][g][e] + b2f(xg[jc][e][g]) + sval * b2f(a0v[g][e]);
                    float ig = sigf(pre[0]), fg = sigf(pre[1]);
                    float gg = tanhft(pre[2]), og = sigf(pre[3]);
                    float cn = fg * cr0[jc][e] + ig * gg;
                    cr0[jc][e] = cn;
                    hv[e] = og * tanhft(cn);
                }
                int lo = __builtin_amdgcn_cvt_pk_fp8_f32(hv[0], hv[1], 0, false);
                hold[jc] = __builtin_amdgcn_cvt_pk_fp8_f32(hv[2], hv[3], lo, true);
            }
            __syncthreads();                          // all done reading h0L
#pragma unroll
            for (int jc = 0; jc < 4; ++jc) {
                int c = (w * 4 + jc) * 2 + (lq >> 1);
                *(int*)(h0L + ln * 512 + ((c ^ ln) << 3) + (lq & 1) * 4) = hold[jc];
            }
            asm volatile("s_waitcnt lgkmcnt(0)" ::: "memory");
            __syncthreads();                          // h0 new visible
        }

        // ====== layer 1: G = W1·[h0;h1]^T, K=1024 (H=64 halves) ===========
        {
            f32x4 acc[4][4];
#pragma unroll
            for (int jc = 0; jc < 4; ++jc)
#pragma unroll
                for (int g = 0; g < 4; ++g) acc[jc][g] = zero;

#pragma unroll 2
            for (int kt = 0; kt < 16; ++kt) {
                long bf = hread(h0L, ln, lq, kt);
                WAIT_VM(8);
                mfma_half<0>(Wr + (size_t)((2 * kt) & 3) * 4096, lane, bf, acc);
                stageH(W1p, w, 2 * kt + 3, Wr, lane);
                WAIT_VM(8);
                mfma_half<8>(Wr + (size_t)((2 * kt + 1) & 3) * 4096, lane, bf, acc);
                stageH(W1p, w, 2 * kt + 4, Wr, lane);
            }
#pragma unroll 2
            for (int kt = 16; kt < 30; ++kt) {
                long bf = hread(h1L, ln, lq, kt - 16);
                WAIT_VM(8);
                mfma_half<0>(Wr + (size_t)((2 * kt) & 3) * 4096, lane, bf, acc);
                stageH(W1p, w, 2 * kt + 3, Wr, lane);
                WAIT_VM(8);
                mfma_half<8>(Wr + (size_t)((2 * kt + 1) & 3) * 4096, lane, bf, acc);
                stageH(W1p, w, 2 * kt + 4, Wr, lane);
            }
            {   // kt = 30: last W1 stage + begin staging next step's layer-0
                long bf = hread(h1L, ln, lq, 14);
                WAIT_VM(8);
                mfma_half<0>(Wr + (size_t)(60 & 3) * 4096, lane, bf, acc);
                stageH(W1p, w, 63, Wr, lane);
                WAIT_VM(8);
                mfma_half<8>(Wr + (size_t)(61 & 3) * 4096, lane, bf, acc);
                stageH(W0p, w, 0, Wr, lane);          // next L0 h0 -> slot 0
            }
            {   // kt = 31
                long bf = hread(h1L, ln, lq, 15);
                WAIT_VM(8);
                mfma_half<0>(Wr + (size_t)(62 & 3) * 4096, lane, bf, acc);
                stageH(W0p, w, 1, Wr, lane);          // next L0 h1 -> slot 1
                WAIT_VM(8);
                mfma_half<8>(Wr + (size_t)(63 & 3) * 4096, lane, bf, acc);
                stageH(W0p, w, 2, Wr, lane);          // next L0 h2 -> slot 2
            }
            int hold[4];
#pragma unroll
            for (int jc = 0; jc < 4; ++jc) {
                int jlb = (w * 4 + jc) * 16 + lq * 4;
                us4 a1v[4];
#pragma unroll
                for (int g = 0; g < 4; ++g) a1v[g] = *(const us4*)(a1Lb + g * 512 + jlb);
                float hv[4];
#pragma unroll
                for (int e = 0; e < 4; ++e) {
                    float pre[4];
#pragma unroll
                    for (int g = 0; g < 4; ++g) pre[g] = acc[jc][g][e] + b2f(a1v[g][e]);
                    float ig = sigf(pre[0]), fg = sigf(pre[1]);
                    float gg = tanhft(pre[2]), og = sigf(pre[3]);
                    float cn = fg * cr1[jc][e] + ig * gg;
                    cr1[jc][e] = cn;
                    hv[e] = og * tanhft(cn);
                }
                int lo = __builtin_amdgcn_cvt_pk_fp8_f32(hv[0], hv[1], 0, false);
                hold[jc] = __builtin_amdgcn_cvt_pk_fp8_f32(hv[2], hv[3], lo, true);
            }
            __syncthreads();                          // all done reading h1L
#pragma unroll
            for (int jc = 0; jc < 4; ++jc) {
                int c = (w * 4 + jc) * 2 + (lq >> 1);
                *(int*)(h1L + ln * 512 + ((c ^ ln) << 3) + (lq & 1) * 4) = hold[jc];
            }
            asm volatile("s_waitcnt lgkmcnt(0)" ::: "memory");
            __syncthreads();                          // h1 new visible
        }
    }

    // ---- final heads on the final h1 (in h1L); stray in-flight loads benign
    head2(Wo1p, bo1, Wo2, bo2[0], false, out, Tsz, 44);
    head2(Wg1p, bg1, Wg2, bg2[0], false, out + (size_t)Bsz * Tsz, 1, 0);
}

// ---------------------------------------------------------------------------
extern "C" void kernel_launch(void* const* d_in, const int* in_sizes, int n_in,
                              void* d_out, int out_size, void* d_ws, size_t ws_size,
                              hipStream_t stream)
{
    const float* ef   = (const float*)d_in[0];
    const float* ctx  = (const float*)d_in[1];
    const float* ii   = (const float*)d_in[2];
    const float* Whi  = (const float*)d_in[3];
    const float* bh   = (const float*)d_in[4];
    const float* Wci  = (const float*)d_in[5];
    const float* bc   = (const float*)d_in[6];
    const float* Wih0 = (const float*)d_in[7];
    const float* Whh0 = (const float*)d_in[8];
    const float* bi0  = (const float*)d_in[9];
    const float* bh0  = (const float*)d_in[10];
    const float* Wih1 = (const float*)d_in[11];
    const float* Whh1 = (const float*)d_in[12];
    const float* bi1  = (const float*)d_in[13];
    const float* bh1  = (const float*)d_in[14];
    const float* Wo1  = (const float*)d_in[15];
    const float* bo1  = (const float*)d_in[16];
    const float* Wo2  = (const float*)d_in[17];
    const float* bo2  = (const float*)d_in[18];
    const float* Wg1  = (const float*)d_in[19];
    const float* bg1  = (const float*)d_in[20];
    const float* Wg2  = (const float*)d_in[21];
    const float* bg2  = (const float*)d_in[22];
    float* out = (float*)d_out;

    char* ws = (char*)d_ws;
    size_t off = 0;
    auto take = [&](size_t bytes) -> char* {
        char* pp = ws + off;
        off += (bytes + 255) & ~(size_t)255;
        return pp;
    };
    u8*  W0p     = (u8*)take(2048ull * 512);
    u8*  W1p     = (u8*)take(2048ull * 1024);
    u8*  Wo1p    = (u8*)take(32ull * 512);
    u8*  Wg1p    = (u8*)take(32ull * 512);
    bf16* Wit    = (bf16*)take(4096ull * 256 * 2);
    bf16* efb    = (bf16*)take((size_t)Bsz * Dsz * 2);
    bf16* ctxb   = (bf16*)take((size_t)Bsz * Dsz * 2);
    u8*  h0x     = (u8*)take((size_t)Bsz * Hsz);
    u8*  h1x     = (u8*)take((size_t)Bsz * Hsz);
    float* c0    = (float*)take((size_t)Bsz * Hsz * 4);
    float* c1    = (float*)take((size_t)Bsz * Hsz * 4);
    bf16* ctxg   = (bf16*)take((size_t)Bsz * 2048 * 2);
    (void)ws_size; (void)in_sizes; (void)n_in; (void)out_size;

    k_conv<<<2048, 256, 0, stream>>>(ef, ctx, Whi, Wci, Wih0, Whh0, Wih1, Whh1, Wo1, Wg1,
                                     efb, ctxb, Wit, W0p, W1p, Wo1p, Wg1p);
    k_init<<<dim3(32, 64), 256, 0, stream>>>(efb, ctxb, Wit, bh, bc, bi0, bh0,
                                             h0x, h1x, c0, c1, ctxg);
    k_loop<<<256, 512, 0, stream>>>(h0x, h1x, W0p, W1p, Wo1p, Wg1p,
                                    ctxg, ii, Wih0, bi1, bh1,
                                    bo1, Wo2, bo2, bg1, Wg2, bg2,
                                    c0, c1, out);
}